// Round 10
// baseline (314.671 us; speedup 1.0000x reference)
//
#include <hip/hip_runtime.h>
#include <hip/hip_bf16.h>

#define N_NODES 25000
#define N_EDGES 400000
#define N_GRAPHS 1000
#define HID 185
#define EPS 1e-5f
#define XPITCH 768            // xcat row pitch (4 * 192), bf16
#define APITCH 36             // LDS row pitch in shorts (18 dwords; conflict-free quarter-wave)

typedef __attribute__((ext_vector_type(8))) short bf16x8;
typedef __attribute__((ext_vector_type(4))) float f32x4;

__device__ __forceinline__ short f2bf(float f) {
    union { float f; unsigned u; } v; v.f = f;
    unsigned r = v.u + 0x7FFFu + ((v.u >> 16) & 1u);   // RNE
    return (short)(r >> 16);
}
__device__ __forceinline__ float bfl(unsigned u) { return __uint_as_float(u << 16); }
__device__ __forceinline__ float bfh(unsigned u) { return __uint_as_float(u & 0xFFFF0000u); }
__device__ __forceinline__ unsigned pk2(float lo, float hi) {
    return (unsigned)(unsigned short)f2bf(lo) | ((unsigned)(unsigned short)f2bf(hi) << 16);
}

// ---- setup: zero cnt + weight transpose/pad/bf16 + BN tables (one kernel) --
#define HW (3 * 192 * 192)
#define JW (192 * 768)
#define CNTPAD 25024
__global__ void k_setup(const float* __restrict__ W_h, const float* __restrict__ W_jk,
                        const float* __restrict__ b0, const float* __restrict__ b_h,
                        const float* __restrict__ gamma, const float* __restrict__ beta,
                        const float* __restrict__ mean, const float* __restrict__ var,
                        int* __restrict__ cnt,
                        short* __restrict__ Wt_h, short* __restrict__ Wt_jk,
                        float* __restrict__ bnsc, float* __restrict__ bnsh) {
    int idx = blockIdx.x * 256 + threadIdx.x;
    if (idx < CNTPAD) { cnt[idx] = 0; return; }
    int p = idx - CNTPAD;
    if (p < HW) {
        int l = p / (192 * 192);
        int r = p % (192 * 192);
        int n = r / 192, k = r % 192;
        float v = (n < HID && k < HID) ? W_h[(l * HID + k) * HID + n] : 0.0f;
        Wt_h[p] = f2bf(v);
    } else if (p < HW + JW) {
        int j2 = p - HW;
        int n = j2 / 768, kk = j2 % 768;
        int l = kk / 192, j = kk % 192;
        float v = (n < HID && j < HID) ? W_jk[(l * HID + j) * HID + n] : 0.0f;
        Wt_jk[j2] = f2bf(v);
    } else if (p < HW + JW + 4 * 192) {
        int li = p - HW - JW;
        int l = li / 192, c = li % 192;
        float sc = 0.0f, sh = 0.0f;
        if (c < HID) {
            float bb = (l == 0) ? b0[c] : b_h[(l - 1) * HID + c];
            sc = rsqrtf(var[l * HID + c] + EPS) * gamma[l * HID + c];
            sh = (bb - mean[l * HID + c]) * sc + beta[l * HID + c];
        }
        bnsc[li] = sc;
        bnsh[li] = sh;
    }
}

__global__ void k_deg(const int* __restrict__ dst, int* cnt, int E) {
    int i = blockIdx.x * blockDim.x + threadIdx.x;
    if (i < E) atomicAdd(&cnt[dst[i]], 1);
}

// ---- single-kernel exclusive scan (block self-sums its prefix) + dis -------
__global__ __launch_bounds__(256) void k_scan(const int* __restrict__ cnt,
                                              int* __restrict__ rowptr,
                                              float* __restrict__ dis, int N) {
    __shared__ int s[256];
    const int t = threadIdx.x;
    const int b = blockIdx.x;
    int partial = 0;
    for (int i = t; i < b * 256; i += 256) partial += cnt[i];
    s[t] = partial; __syncthreads();
    for (int off = 128; off; off >>= 1) {
        if (t < off) s[t] += s[t + off];
        __syncthreads();
    }
    const int base = s[0];
    __syncthreads();
    int i = b * 256 + t;
    int v = (i < N) ? cnt[i] : 0;
    if (i < N) dis[i] = rsqrtf((float)(v + 1));
    s[t] = v; __syncthreads();
    for (int off = 1; off < 256; off <<= 1) {
        int x2 = (t >= off) ? s[t - off] : 0;
        __syncthreads();
        s[t] += x2;
        __syncthreads();
    }
    if (i < N) rowptr[i] = base + s[t] - v;   // exclusive
}

// ---- scatter: bump rowptr (post: rowptr[n]=end; begin = n?rowptr[n-1]:0) ---
__global__ void k_scatter(const int* __restrict__ src, const int* __restrict__ dst,
                          const float* __restrict__ dis,
                          int* rowptr, int2* __restrict__ csr, int E) {
    int e = blockIdx.x * blockDim.x + threadIdx.x;
    if (e < E) {
        int d = dst[e];
        int s = src[e];
        int o = atomicAdd(&rowptr[d], 1);
        csr[o] = make_int2(s, __float_as_int(dis[s]));
    }
}

// ---- layer-0 aggregation in 9-ch input space (unroll-4) --------------------
__global__ void k_aggr0(const float* __restrict__ x, const float* __restrict__ dis,
                        const int* __restrict__ rowptr, const int2* __restrict__ csr,
                        float* __restrict__ xa, int N) {
    int idx = blockIdx.x * blockDim.x + threadIdx.x;
    int n = idx >> 4;
    int c = idx & 15;
    if (n >= N || c >= 9) return;
    float dn = dis[n];
    float acc = x[n * 9 + c] * dn;
    int end = rowptr[n];
    int e = n ? rowptr[n - 1] : 0;
    for (; e + 4 <= end; e += 4) {
        int2 p0 = csr[e], p1 = csr[e + 1], p2 = csr[e + 2], p3 = csr[e + 3];
        acc += x[p0.x * 9 + c] * __int_as_float(p0.y)
             + x[p1.x * 9 + c] * __int_as_float(p1.y)
             + x[p2.x * 9 + c] * __int_as_float(p2.y)
             + x[p3.x * 9 + c] * __int_as_float(p3.y);
    }
    for (; e < end; ++e) {
        int2 p = csr[e];
        acc += x[p.x * 9 + c] * __int_as_float(p.y);
    }
    xa[n * 9 + c] = acc * dn;
}

// ---- layer-0 GEMM (fp32 vector, K=9) + BN + ReLU -> bf16 xcat slice 0 ------
__global__ __launch_bounds__(192) void k_gemm0(const float* __restrict__ A,
                                               const float* __restrict__ W,
                                               const float* __restrict__ bnsc,
                                               const float* __restrict__ bnsh,
                                               short* __restrict__ xcat, int N) {
    __shared__ float As[8 * 9];
    const int tid = threadIdx.x;
    const int r0 = blockIdx.x * 8;
    for (int idx = tid; idx < 72; idx += 192) {
        int r = idx & 7, k = idx >> 3;
        int row = r0 + r;
        As[idx] = (row < N) ? A[row * 9 + k] : 0.0f;
    }
    __syncthreads();
    const int c = tid;   // 0..191
    float res[8];
    #pragma unroll
    for (int r = 0; r < 8; ++r) res[r] = 0.0f;
    if (c < HID) {
        float acc[8] = {0,0,0,0,0,0,0,0};
        for (int k = 0; k < 9; ++k) {
            float w = W[k * HID + c];
            #pragma unroll
            for (int r = 0; r < 8; ++r) acc[r] += As[k * 8 + r] * w;
        }
        float sc = bnsc[c], sh = bnsh[c];
        #pragma unroll
        for (int r = 0; r < 8; ++r)
            res[r] = fmaxf(acc[r] * sc + sh, 0.0f);
    }
    #pragma unroll
    for (int r = 0; r < 8; ++r) {
        int row = r0 + r;
        if (row < N) xcat[row * XPITCH + c] = (c < HID) ? f2bf(res[r]) : (short)0;
    }
}

// ---- fused layer (1..3): aggregate 64 nodes into LDS A-tile, then MFMA -----
// Phase 1: thread t -> node r0+(t>>2), col group (t&3)*48; f32 accumulate
// dn*(x_n*dn + sum w*x_src) over 48 cols; pack bf16 into As (chunk-major,
// [kc][64 x APITCH] — the R8-proven conflict-free fragment layout).
// Phase 2: R8 K-loop (B staged per chunk), BN+ReLU epilogue -> xcat slice.
__global__ __launch_bounds__(256) void k_layer(const short* __restrict__ feat,
                                               const float* __restrict__ dis,
                                               const int* __restrict__ rowptr,
                                               const int2* __restrict__ csr,
                                               const short* __restrict__ Bt,
                                               const float* __restrict__ bnsc,
                                               const float* __restrict__ bnsh,
                                               short* __restrict__ outp, int N) {
    __shared__ short As[6 * 64 * APITCH];   // 6 chunks x 64 rows x 36
    __shared__ short Bs[192 * APITCH];
    const int tid = threadIdx.x;
    const int r0 = blockIdx.x * 64;

    // ---- phase 1: aggregation into As ----
    {
        const int r = tid >> 2;          // 0..63
        const int c0 = (tid & 3) * 48;   // col group base
        const int n = r0 + r;
        float a[48];
        if (n < N) {
            float dn = dis[n];
            const short* fr = feat + (size_t)n * XPITCH + c0;
            #pragma unroll
            for (int i = 0; i < 12; ++i) {
                uint2 v = *(const uint2*)(fr + i * 4);
                a[i*4+0] = bfl(v.x) * dn; a[i*4+1] = bfh(v.x) * dn;
                a[i*4+2] = bfl(v.y) * dn; a[i*4+3] = bfh(v.y) * dn;
            }
            int end = rowptr[n];
            int e = n ? rowptr[n - 1] : 0;
            for (; e < end; ++e) {
                int2 p = csr[e];
                float w = __int_as_float(p.y);
                const short* fs = feat + (size_t)p.x * XPITCH + c0;
                #pragma unroll
                for (int i = 0; i < 12; ++i) {
                    uint2 v = *(const uint2*)(fs + i * 4);
                    a[i*4+0] += bfl(v.x) * w; a[i*4+1] += bfh(v.x) * w;
                    a[i*4+2] += bfl(v.y) * w; a[i*4+3] += bfh(v.y) * w;
                }
            }
            #pragma unroll
            for (int i = 0; i < 48; ++i) a[i] *= dn;
        } else {
            #pragma unroll
            for (int i = 0; i < 48; ++i) a[i] = 0.0f;
        }
        #pragma unroll
        for (int i = 0; i < 24; ++i) {
            int c = c0 + 2 * i;
            int kc = c >> 5, off = c & 31;
            *(unsigned*)(As + kc * 64 * APITCH + r * APITCH + off) = pk2(a[2*i], a[2*i+1]);
        }
    }
    __syncthreads();

    // ---- phase 2: GEMM (K=192), A from LDS, B per-chunk staging ----
    const int wave = tid >> 6;
    const int lane = tid & 63;
    const int quad = lane >> 4;
    const int lm = lane & 15;

    f32x4 acc[4][3];
    #pragma unroll
    for (int i = 0; i < 4; ++i)
        #pragma unroll
        for (int j = 0; j < 3; ++j) acc[i][j] = (f32x4){0.f, 0.f, 0.f, 0.f};

    for (int kc = 0; kc < 6; ++kc) {
        const int k0 = kc * 32;
        #pragma unroll
        for (int i = 0; i < 3; ++i) {   // stage B: 192 rows x 32 k
            int u = tid + i * 256;
            int nb = u >> 2, seg = u & 3;
            bf16x8 v = *(const bf16x8*)(Bt + nb * 192 + k0 + seg * 8);
            *(bf16x8*)(Bs + nb * APITCH + seg * 8) = v;
        }
        __syncthreads();
        bf16x8 a[4], b[3];
        #pragma unroll
        for (int mt = 0; mt < 4; ++mt)
            a[mt] = *(const bf16x8*)(As + kc * 64 * APITCH + (mt * 16 + lm) * APITCH + quad * 8);
        #pragma unroll
        for (int nt = 0; nt < 3; ++nt)
            b[nt] = *(const bf16x8*)(Bs + (wave * 48 + nt * 16 + lm) * APITCH + quad * 8);
        #pragma unroll
        for (int mt = 0; mt < 4; ++mt)
            #pragma unroll
            for (int nt = 0; nt < 3; ++nt)
                acc[mt][nt] = __builtin_amdgcn_mfma_f32_16x16x32_bf16(a[mt], b[nt], acc[mt][nt], 0, 0, 0);
        __syncthreads();
    }
    // epilogue: BN + ReLU, write bf16 to xcat slice (pitch XPITCH)
    #pragma unroll
    for (int nt = 0; nt < 3; ++nt) {
        int col = wave * 48 + nt * 16 + lm;
        float sc = bnsc[col], sh = bnsh[col];
        #pragma unroll
        for (int mt = 0; mt < 4; ++mt) {
            #pragma unroll
            for (int r = 0; r < 4; ++r) {
                int row = r0 + mt * 16 + quad * 4 + r;
                if (row < N)
                    outp[(size_t)row * XPITCH + col] = f2bf(fmaxf(acc[mt][nt][r] * sc + sh, 0.0f));
            }
        }
    }
}

// ---- bf16 MFMA GEMM (R8 v1 structure) for JK: C = A[N x 768] @ Bt^T --------
template<int KCH>
__global__ __launch_bounds__(256) void k_mgemm(const short* __restrict__ A, int apitch,
                                               const short* __restrict__ Bt,
                                               short* __restrict__ Cout, int cpitch, int N) {
    __shared__ short As[64 * APITCH];
    __shared__ short Bs[192 * APITCH];
    const int tid = threadIdx.x;
    const int wave = tid >> 6;
    const int lane = tid & 63;
    const int quad = lane >> 4;
    const int lm = lane & 15;
    const int r0 = blockIdx.x * 64;
    const int KTOT = KCH * 32;
    const int arow = tid >> 2, aseg = tid & 3;

    f32x4 acc[4][3];
    #pragma unroll
    for (int i = 0; i < 4; ++i)
        #pragma unroll
        for (int j = 0; j < 3; ++j) acc[i][j] = (f32x4){0.f, 0.f, 0.f, 0.f};

    for (int kc = 0; kc < KCH; ++kc) {
        const int k0 = kc * 32;
        {   // stage A: 64 rows x 32 k (16B per thread)
            int grow = r0 + arow;
            bf16x8 v = (bf16x8){0,0,0,0,0,0,0,0};
            if (grow < N) v = *(const bf16x8*)(A + (size_t)grow * apitch + k0 + aseg * 8);
            *(bf16x8*)(As + arow * APITCH + aseg * 8) = v;
        }
        #pragma unroll
        for (int i = 0; i < 3; ++i) {   // stage B: 192 rows x 32 k
            int u = tid + i * 256;
            int n = u >> 2, seg = u & 3;
            bf16x8 v = *(const bf16x8*)(Bt + n * KTOT + k0 + seg * 8);
            *(bf16x8*)(Bs + n * APITCH + seg * 8) = v;
        }
        __syncthreads();
        bf16x8 a[4], b[3];
        #pragma unroll
        for (int mt = 0; mt < 4; ++mt)
            a[mt] = *(const bf16x8*)(As + (mt * 16 + lm) * APITCH + quad * 8);
        #pragma unroll
        for (int nt = 0; nt < 3; ++nt)
            b[nt] = *(const bf16x8*)(Bs + (wave * 48 + nt * 16 + lm) * APITCH + quad * 8);
        #pragma unroll
        for (int mt = 0; mt < 4; ++mt)
            #pragma unroll
            for (int nt = 0; nt < 3; ++nt)
                acc[mt][nt] = __builtin_amdgcn_mfma_f32_16x16x32_bf16(a[mt], b[nt], acc[mt][nt], 0, 0, 0);
        __syncthreads();
    }
    #pragma unroll
    for (int nt = 0; nt < 3; ++nt) {
        int col = wave * 48 + nt * 16 + lm;
        #pragma unroll
        for (int mt = 0; mt < 4; ++mt) {
            #pragma unroll
            for (int r = 0; r < 4; ++r) {
                int row = r0 + mt * 16 + quad * 4 + r;
                if (row < N) Cout[(size_t)row * cpitch + col] = f2bf(acc[mt][nt][r]);
            }
        }
    }
}

// ---- segmented global-max-pool + bias + final dense, one block per graph ---
__global__ __launch_bounds__(192) void k_pool_out(const short* __restrict__ jk,
                                                  const int* __restrict__ batch,
                                                  const float* __restrict__ b_jk,
                                                  const float* __restrict__ W_out,
                                                  const float* __restrict__ b_out,
                                                  float* __restrict__ out, int N) {
    __shared__ int bounds[2];
    __shared__ float partial[3];
    const int g = blockIdx.x;
    const int tid = threadIdx.x;
    if (tid < 2) {
        int key = g + tid;              // lower_bound(batch, key)
        int lo = 0, hi = N;
        while (lo < hi) {
            int mid = (lo + hi) >> 1;
            if (batch[mid] < key) lo = mid + 1; else hi = mid;
        }
        bounds[tid] = lo;
    }
    __syncthreads();
    const int beg = bounds[0], end = bounds[1];
    float mx = -3.4e38f;
    for (int n = beg; n < end; ++n)
        mx = fmaxf(mx, bfl((unsigned)(unsigned short)jk[(size_t)n * 192 + tid]));
    float p = (tid < HID) ? (mx + b_jk[tid]) * W_out[tid] : 0.0f;
    #pragma unroll
    for (int off = 32; off; off >>= 1) p += __shfl_down(p, off);
    if ((tid & 63) == 0) partial[tid >> 6] = p;
    __syncthreads();
    if (tid == 0) out[g] = partial[0] + partial[1] + partial[2] + b_out[0];
}

extern "C" void kernel_launch(void* const* d_in, const int* in_sizes, int n_in,
                              void* d_out, int out_size, void* d_ws, size_t ws_size,
                              hipStream_t stream) {
    const float* x      = (const float*)d_in[0];
    const int*   ei     = (const int*)  d_in[1];
    const int*   batch  = (const int*)  d_in[2];
    const float* W0     = (const float*)d_in[3];
    const float* b0     = (const float*)d_in[4];
    const float* W_h    = (const float*)d_in[5];
    const float* b_h    = (const float*)d_in[6];
    const float* gamma  = (const float*)d_in[7];
    const float* beta   = (const float*)d_in[8];
    const float* mean   = (const float*)d_in[9];
    const float* var    = (const float*)d_in[10];
    const float* W_jk   = (const float*)d_in[11];
    const float* b_jk   = (const float*)d_in[12];
    const float* W_out  = (const float*)d_in[13];
    const float* b_out  = (const float*)d_in[14];
    float* out = (float*)d_out;

    const int N = N_NODES, E = N_EDGES, G = N_GRAPHS;
    const int NB = (N + 255) / 256;   // 98

    // workspace layout (8B-aligned chunks)
    float* dis   = (float*)d_ws;                    // 25,024
    float* xa    = dis + 25024;                     // 225,024
    float* bnsc  = xa + 225024;                     // 768
    float* bnsh  = bnsc + 768;                      // 768
    int2*  csr   = (int2*)(bnsh + 768);             // 400,000 int2 (8B aligned)
    short* xcat  = (short*)(csr + 400000);          // 19,200,000 shorts
    short* tmp16 = xcat + 19200000;                 // 4,800,000 shorts (JK out)
    short* Wt_h  = tmp16 + 4800000;                 // 110,592 shorts
    short* Wt_jk = Wt_h + 110592;                   // 147,456 shorts
    int* rowptr  = (int*)(Wt_jk + 147456);          // 25,024
    int* cnt     = rowptr + 25024;                  // 25,024

    const int* src = ei;
    const int* dst = ei + E;

    k_setup<<<(CNTPAD + HW + JW + 4 * 192 + 255) / 256, 256, 0, stream>>>(
        W_h, W_jk, b0, b_h, gamma, beta, mean, var, cnt, Wt_h, Wt_jk, bnsc, bnsh);
    k_deg<<<(E + 255) / 256, 256, 0, stream>>>(dst, cnt, E);
    k_scan<<<NB, 256, 0, stream>>>(cnt, rowptr, dis, N);
    k_scatter<<<(E + 255) / 256, 256, 0, stream>>>(src, dst, dis, rowptr, csr, E);

    // layer 0: aggregate in 9-ch space, then GEMM(K=9) + BN + ReLU
    k_aggr0<<<(N * 16 + 255) / 256, 256, 0, stream>>>(x, dis, rowptr, csr, xa, N);
    k_gemm0<<<(N + 7) / 8, 192, 0, stream>>>(xa, W0, bnsc, bnsh, xcat, N);

    // layers 1..3: fused aggregate + GEMM + BN + ReLU
    const int MB = (N + 63) / 64;   // 391
    for (int l = 1; l < 4; ++l) {
        k_layer<<<MB, 256, 0, stream>>>(xcat + (l - 1) * 192, dis, rowptr, csr,
                                        Wt_h + (l - 1) * 192 * 192,
                                        bnsc + l * 192, bnsh + l * 192,
                                        xcat + l * 192, N);
    }

    // JK: [N x 768] @ [768 x 192] -> bf16 tmp16 (bias folded into pool)
    k_mgemm<24><<<MB, 256, 0, stream>>>(xcat, XPITCH, Wt_jk, tmp16, 192, N);

    // segmented max pool + bias + output dense, no atomics
    k_pool_out<<<G, 192, 0, stream>>>(tmp16, batch, b_jk, W_out, b_out, out, N);
}

// Round 11
// 300.692 us; speedup vs baseline: 1.0465x; 1.0465x over previous
//
#include <hip/hip_runtime.h>
#include <hip/hip_bf16.h>

#define N_NODES 25000
#define N_EDGES 400000
#define N_GRAPHS 1000
#define HID 185
#define EPS 1e-5f
#define XPITCH 768            // xcat row pitch (4 * 192), bf16
#define APITCH 36             // LDS row pitch in shorts (18 dwords; conflict-free quarter-wave)

typedef __attribute__((ext_vector_type(8))) short bf16x8;
typedef __attribute__((ext_vector_type(4))) float f32x4;

__device__ __forceinline__ short f2bf(float f) {
    union { float f; unsigned u; } v; v.f = f;
    unsigned r = v.u + 0x7FFFu + ((v.u >> 16) & 1u);   // RNE
    return (short)(r >> 16);
}
__device__ __forceinline__ float bfl(unsigned u) { return __uint_as_float(u << 16); }
__device__ __forceinline__ float bfh(unsigned u) { return __uint_as_float(u & 0xFFFF0000u); }
__device__ __forceinline__ unsigned pk2(float lo, float hi) {
    return (unsigned)(unsigned short)f2bf(lo) | ((unsigned)(unsigned short)f2bf(hi) << 16);
}
// packed CSR entry: high 16 = bf16 weight, low 16 = src index (N < 65536)
__device__ __forceinline__ int csr_idx(unsigned p) { return (int)(p & 0xFFFFu); }
__device__ __forceinline__ float csr_wgt(unsigned p) { return bfh(p); }

// ---- setup: zero cnt + weight transpose/pad/bf16 + BN tables (one kernel) --
#define HW (3 * 192 * 192)
#define JW (192 * 768)
#define CNTPAD 25024
__global__ void k_setup(const float* __restrict__ W_h, const float* __restrict__ W_jk,
                        const float* __restrict__ b0, const float* __restrict__ b_h,
                        const float* __restrict__ gamma, const float* __restrict__ beta,
                        const float* __restrict__ mean, const float* __restrict__ var,
                        int* __restrict__ cnt,
                        short* __restrict__ Wt_h, short* __restrict__ Wt_jk,
                        float* __restrict__ bnsc, float* __restrict__ bnsh) {
    int idx = blockIdx.x * 256 + threadIdx.x;
    if (idx < CNTPAD) { cnt[idx] = 0; return; }
    int p = idx - CNTPAD;
    if (p < HW) {
        int l = p / (192 * 192);
        int r = p % (192 * 192);
        int n = r / 192, k = r % 192;
        float v = (n < HID && k < HID) ? W_h[(l * HID + k) * HID + n] : 0.0f;
        Wt_h[p] = f2bf(v);
    } else if (p < HW + JW) {
        int j2 = p - HW;
        int n = j2 / 768, kk = j2 % 768;
        int l = kk / 192, j = kk % 192;
        float v = (n < HID && j < HID) ? W_jk[(l * HID + j) * HID + n] : 0.0f;
        Wt_jk[j2] = f2bf(v);
    } else if (p < HW + JW + 4 * 192) {
        int li = p - HW - JW;
        int l = li / 192, c = li % 192;
        float sc = 0.0f, sh = 0.0f;
        if (c < HID) {
            float bb = (l == 0) ? b0[c] : b_h[(l - 1) * HID + c];
            sc = rsqrtf(var[l * HID + c] + EPS) * gamma[l * HID + c];
            sh = (bb - mean[l * HID + c]) * sc + beta[l * HID + c];
        }
        bnsc[li] = sc;
        bnsh[li] = sh;
    }
}

__global__ void k_deg(const int* __restrict__ dst, int* cnt, int E) {
    int i = blockIdx.x * blockDim.x + threadIdx.x;
    if (i < E) atomicAdd(&cnt[dst[i]], 1);
}

// ---- scan phase 1: per-block sums (+ dis) ----------------------------------
__global__ __launch_bounds__(256) void k_scan_part(const int* __restrict__ cnt,
                                                   int* __restrict__ bsum,
                                                   float* __restrict__ dis, int N) {
    int i = blockIdx.x * 256 + threadIdx.x;
    int v = (i < N) ? cnt[i] : 0;
    if (i < N) dis[i] = rsqrtf((float)(v + 1));
    #pragma unroll
    for (int off = 32; off; off >>= 1) v += __shfl_down(v, off);
    __shared__ int s[4];
    if ((threadIdx.x & 63) == 0) s[threadIdx.x >> 6] = v;
    __syncthreads();
    if (threadIdx.x == 0) bsum[blockIdx.x] = s[0] + s[1] + s[2] + s[3];
}

// ---- scan phase 2: exclusive prefix -> rowptr[i] (block base from bsum) ----
__global__ __launch_bounds__(256) void k_scan_add(const int* __restrict__ cnt,
                                                  const int* __restrict__ bsum,
                                                  int* __restrict__ rowptr, int N) {
    __shared__ int s[256];
    const int t = threadIdx.x;
    const int b = blockIdx.x;
    int partial = 0;
    for (int i = t; i < b; i += 256) partial += bsum[i];
    s[t] = partial; __syncthreads();
    for (int off = 128; off; off >>= 1) {
        if (t < off) s[t] += s[t + off];
        __syncthreads();
    }
    const int base = s[0];
    __syncthreads();
    int i = b * 256 + t;
    int v = (i < N) ? cnt[i] : 0;
    s[t] = v; __syncthreads();
    for (int off = 1; off < 256; off <<= 1) {
        int x2 = (t >= off) ? s[t - off] : 0;
        __syncthreads();
        s[t] += x2;
        __syncthreads();
    }
    if (i < N) rowptr[i] = base + s[t] - v;   // exclusive
}

// ---- scatter: bump rowptr (post: rowptr[n]=end; begin = n?rowptr[n-1]:0) ---
// 4B packed entry: (bf16(dis[src]) << 16) | src
__global__ void k_scatter(const int* __restrict__ src, const int* __restrict__ dst,
                          const float* __restrict__ dis,
                          int* rowptr, unsigned* __restrict__ csr, int E) {
    int e = blockIdx.x * blockDim.x + threadIdx.x;
    if (e < E) {
        int d = dst[e];
        int s = src[e];
        int o = atomicAdd(&rowptr[d], 1);
        csr[o] = ((unsigned)(unsigned short)f2bf(dis[s]) << 16) | (unsigned)s;
    }
}

// ---- layer-0 aggregation in 9-ch input space (unroll-4) --------------------
__global__ void k_aggr0(const float* __restrict__ x, const float* __restrict__ dis,
                        const int* __restrict__ rowptr, const unsigned* __restrict__ csr,
                        float* __restrict__ xa, int N) {
    int idx = blockIdx.x * blockDim.x + threadIdx.x;
    int n = idx >> 4;
    int c = idx & 15;
    if (n >= N || c >= 9) return;
    float dn = dis[n];
    float acc = x[n * 9 + c] * dn;
    int end = rowptr[n];
    int e = n ? rowptr[n - 1] : 0;
    for (; e + 4 <= end; e += 4) {
        unsigned p0 = csr[e], p1 = csr[e + 1], p2 = csr[e + 2], p3 = csr[e + 3];
        acc += x[csr_idx(p0) * 9 + c] * csr_wgt(p0)
             + x[csr_idx(p1) * 9 + c] * csr_wgt(p1)
             + x[csr_idx(p2) * 9 + c] * csr_wgt(p2)
             + x[csr_idx(p3) * 9 + c] * csr_wgt(p3);
    }
    for (; e < end; ++e) {
        unsigned p = csr[e];
        acc += x[csr_idx(p) * 9 + c] * csr_wgt(p);
    }
    xa[n * 9 + c] = acc * dn;
}

// ---- layer-0 GEMM (fp32 vector, K=9) + BN + ReLU -> bf16 xcat slice 0 ------
__global__ __launch_bounds__(192) void k_gemm0(const float* __restrict__ A,
                                               const float* __restrict__ W,
                                               const float* __restrict__ bnsc,
                                               const float* __restrict__ bnsh,
                                               short* __restrict__ xcat, int N) {
    __shared__ float As[8 * 9];
    const int tid = threadIdx.x;
    const int r0 = blockIdx.x * 8;
    for (int idx = tid; idx < 72; idx += 192) {
        int r = idx & 7, k = idx >> 3;
        int row = r0 + r;
        As[idx] = (row < N) ? A[row * 9 + k] : 0.0f;
    }
    __syncthreads();
    const int c = tid;   // 0..191
    float res[8];
    #pragma unroll
    for (int r = 0; r < 8; ++r) res[r] = 0.0f;
    if (c < HID) {
        float acc[8] = {0,0,0,0,0,0,0,0};
        for (int k = 0; k < 9; ++k) {
            float w = W[k * HID + c];
            #pragma unroll
            for (int r = 0; r < 8; ++r) acc[r] += As[k * 8 + r] * w;
        }
        float sc = bnsc[c], sh = bnsh[c];
        #pragma unroll
        for (int r = 0; r < 8; ++r)
            res[r] = fmaxf(acc[r] * sc + sh, 0.0f);
    }
    #pragma unroll
    for (int r = 0; r < 8; ++r) {
        int row = r0 + r;
        if (row < N) xcat[row * XPITCH + c] = (c < HID) ? f2bf(res[r]) : (short)0;
    }
}

// ---- bf16 MFMA GEMM (R8 structure, best measured) --------------------------
// C[N x 192] = A[N x KCH*32] @ Bt^T, bf16 out at pitch 192; A pitch XPITCH.
template<int KCH>
__global__ __launch_bounds__(256) void k_mgemm(const short* __restrict__ A,
                                               const short* __restrict__ Bt,
                                               short* __restrict__ Cout, int N) {
    __shared__ short As[64 * APITCH];
    __shared__ short Bs[192 * APITCH];
    const int tid = threadIdx.x;
    const int wave = tid >> 6;
    const int lane = tid & 63;
    const int quad = lane >> 4;
    const int lm = lane & 15;
    const int r0 = blockIdx.x * 64;
    const int KTOT = KCH * 32;
    const int arow = tid >> 2, aseg = tid & 3;

    f32x4 acc[4][3];
    #pragma unroll
    for (int i = 0; i < 4; ++i)
        #pragma unroll
        for (int j = 0; j < 3; ++j) acc[i][j] = (f32x4){0.f, 0.f, 0.f, 0.f};

    for (int kc = 0; kc < KCH; ++kc) {
        const int k0 = kc * 32;
        {   // stage A: 64 rows x 32 k (16B per thread)
            int grow = r0 + arow;
            bf16x8 v = (bf16x8){0,0,0,0,0,0,0,0};
            if (grow < N) v = *(const bf16x8*)(A + (size_t)grow * XPITCH + k0 + aseg * 8);
            *(bf16x8*)(As + arow * APITCH + aseg * 8) = v;
        }
        #pragma unroll
        for (int i = 0; i < 3; ++i) {   // stage B: 192 rows x 32 k
            int u = tid + i * 256;
            int n = u >> 2, seg = u & 3;
            bf16x8 v = *(const bf16x8*)(Bt + n * KTOT + k0 + seg * 8);
            *(bf16x8*)(Bs + n * APITCH + seg * 8) = v;
        }
        __syncthreads();
        bf16x8 a[4], b[3];
        #pragma unroll
        for (int mt = 0; mt < 4; ++mt)
            a[mt] = *(const bf16x8*)(As + (mt * 16 + lm) * APITCH + quad * 8);
        #pragma unroll
        for (int nt = 0; nt < 3; ++nt)
            b[nt] = *(const bf16x8*)(Bs + (wave * 48 + nt * 16 + lm) * APITCH + quad * 8);
        #pragma unroll
        for (int mt = 0; mt < 4; ++mt)
            #pragma unroll
            for (int nt = 0; nt < 3; ++nt)
                acc[mt][nt] = __builtin_amdgcn_mfma_f32_16x16x32_bf16(a[mt], b[nt], acc[mt][nt], 0, 0, 0);
        __syncthreads();
    }
    // epilogue: D[row][col], col = wave*48+nt*16+lm, row = r0+mt*16+quad*4+r
    #pragma unroll
    for (int mt = 0; mt < 4; ++mt) {
        #pragma unroll
        for (int nt = 0; nt < 3; ++nt) {
            int col = wave * 48 + nt * 16 + lm;
            #pragma unroll
            for (int r = 0; r < 4; ++r) {
                int row = r0 + mt * 16 + quad * 4 + r;
                if (row < N) Cout[row * 192 + col] = f2bf(acc[mt][nt][r]);
            }
        }
    }
}

// ---- fused aggregation + BN + ReLU (layers 1..3) ---------------------------
// one node per wave; lane covers 4 channels (uint2 = 4 bf16), 48 active lanes
__global__ __launch_bounds__(256) void k_aggr_bn(const short* __restrict__ tmp16,
                                                 const float* __restrict__ dis,
                                                 const int* __restrict__ rowptr,
                                                 const unsigned* __restrict__ csr,
                                                 const float* __restrict__ bnsc,
                                                 const float* __restrict__ bnsh,
                                                 short* __restrict__ outp, int N) {
    int n = (blockIdx.x << 2) + (threadIdx.x >> 6);
    if (n >= N) return;
    int lane = threadIdx.x & 63;
    int c0 = (lane < 48) ? (lane << 2) : 0;
    float dn = dis[n];
    float a0, a1, a2, a3;
    {
        uint2 v = *(const uint2*)(tmp16 + (size_t)n * 192 + c0);
        a0 = bfl(v.x) * dn; a1 = bfh(v.x) * dn; a2 = bfl(v.y) * dn; a3 = bfh(v.y) * dn;
    }
    int end = rowptr[n];
    int e = n ? rowptr[n - 1] : 0;
    for (; e + 4 <= end; e += 4) {
        unsigned p0 = csr[e], p1 = csr[e + 1], p2 = csr[e + 2], p3 = csr[e + 3];
        float w0 = csr_wgt(p0), w1 = csr_wgt(p1), w2 = csr_wgt(p2), w3 = csr_wgt(p3);
        uint2 v0 = *(const uint2*)(tmp16 + (size_t)csr_idx(p0) * 192 + c0);
        uint2 v1 = *(const uint2*)(tmp16 + (size_t)csr_idx(p1) * 192 + c0);
        uint2 v2 = *(const uint2*)(tmp16 + (size_t)csr_idx(p2) * 192 + c0);
        uint2 v3 = *(const uint2*)(tmp16 + (size_t)csr_idx(p3) * 192 + c0);
        a0 += bfl(v0.x) * w0; a1 += bfh(v0.x) * w0; a2 += bfl(v0.y) * w0; a3 += bfh(v0.y) * w0;
        a0 += bfl(v1.x) * w1; a1 += bfh(v1.x) * w1; a2 += bfl(v1.y) * w1; a3 += bfh(v1.y) * w1;
        a0 += bfl(v2.x) * w2; a1 += bfh(v2.x) * w2; a2 += bfl(v2.y) * w2; a3 += bfh(v2.y) * w2;
        a0 += bfl(v3.x) * w3; a1 += bfh(v3.x) * w3; a2 += bfl(v3.y) * w3; a3 += bfh(v3.y) * w3;
    }
    for (; e < end; ++e) {
        unsigned p = csr[e];
        float w = csr_wgt(p);
        uint2 v = *(const uint2*)(tmp16 + (size_t)csr_idx(p) * 192 + c0);
        a0 += bfl(v.x) * w; a1 += bfh(v.x) * w; a2 += bfl(v.y) * w; a3 += bfh(v.y) * w;
    }
    float4 sc = *(const float4*)(bnsc + c0);
    float4 sh = *(const float4*)(bnsh + c0);
    float o0 = fmaxf(a0 * dn * sc.x + sh.x, 0.0f);
    float o1 = fmaxf(a1 * dn * sc.y + sh.y, 0.0f);
    float o2 = fmaxf(a2 * dn * sc.z + sh.z, 0.0f);
    float o3 = fmaxf(a3 * dn * sc.w + sh.w, 0.0f);
    if (lane < 48) {
        uint2 p;
        p.x = pk2(o0, o1);
        p.y = pk2(o2, o3);
        *(uint2*)(outp + (size_t)n * XPITCH + c0) = p;
    }
}

// ---- segmented global-max-pool + bias + final dense, one block per graph ---
__global__ __launch_bounds__(192) void k_pool_out(const short* __restrict__ jk,
                                                  const int* __restrict__ batch,
                                                  const float* __restrict__ b_jk,
                                                  const float* __restrict__ W_out,
                                                  const float* __restrict__ b_out,
                                                  float* __restrict__ out, int N) {
    __shared__ int bounds[2];
    __shared__ float partial[3];
    const int g = blockIdx.x;
    const int tid = threadIdx.x;
    if (tid < 2) {
        int key = g + tid;              // lower_bound(batch, key)
        int lo = 0, hi = N;
        while (lo < hi) {
            int mid = (lo + hi) >> 1;
            if (batch[mid] < key) lo = mid + 1; else hi = mid;
        }
        bounds[tid] = lo;
    }
    __syncthreads();
    const int beg = bounds[0], end = bounds[1];
    float mx = -3.4e38f;
    for (int n = beg; n < end; ++n)
        mx = fmaxf(mx, bfl((unsigned)(unsigned short)jk[(size_t)n * 192 + tid]));
    float p = (tid < HID) ? (mx + b_jk[tid]) * W_out[tid] : 0.0f;
    #pragma unroll
    for (int off = 32; off; off >>= 1) p += __shfl_down(p, off);
    if ((tid & 63) == 0) partial[tid >> 6] = p;
    __syncthreads();
    if (tid == 0) out[g] = partial[0] + partial[1] + partial[2] + b_out[0];
}

extern "C" void kernel_launch(void* const* d_in, const int* in_sizes, int n_in,
                              void* d_out, int out_size, void* d_ws, size_t ws_size,
                              hipStream_t stream) {
    const float* x      = (const float*)d_in[0];
    const int*   ei     = (const int*)  d_in[1];
    const int*   batch  = (const int*)  d_in[2];
    const float* W0     = (const float*)d_in[3];
    const float* b0     = (const float*)d_in[4];
    const float* W_h    = (const float*)d_in[5];
    const float* b_h    = (const float*)d_in[6];
    const float* gamma  = (const float*)d_in[7];
    const float* beta   = (const float*)d_in[8];
    const float* mean   = (const float*)d_in[9];
    const float* var    = (const float*)d_in[10];
    const float* W_jk   = (const float*)d_in[11];
    const float* b_jk   = (const float*)d_in[12];
    const float* W_out  = (const float*)d_in[13];
    const float* b_out  = (const float*)d_in[14];
    float* out = (float*)d_out;

    const int N = N_NODES, E = N_EDGES, G = N_GRAPHS;
    const int NB = (N + 255) / 256;   // 98

    // workspace layout (8B-aligned chunks)
    float* dis   = (float*)d_ws;                    // 25,024
    float* xa    = dis + 25024;                     // 225,024
    float* bnsc  = xa + 225024;                     // 768
    float* bnsh  = bnsc + 768;                      // 768
    unsigned* csr = (unsigned*)(bnsh + 768);        // 400,000 packed entries
    short* xcat  = (short*)(csr + 400000);          // 19,200,000 shorts
    short* tmp16 = xcat + 19200000;                 // 4,800,000 shorts (aggr in / JK out)
    short* Wt_h  = tmp16 + 4800000;                 // 110,592 shorts
    short* Wt_jk = Wt_h + 110592;                   // 147,456 shorts
    int* rowptr  = (int*)(Wt_jk + 147456);          // 25,024
    int* cnt     = rowptr + 25024;                  // 25,024
    int* bsum    = cnt + 25024;                     // 128

    const int* src = ei;
    const int* dst = ei + E;

    k_setup<<<(CNTPAD + HW + JW + 4 * 192 + 255) / 256, 256, 0, stream>>>(
        W_h, W_jk, b0, b_h, gamma, beta, mean, var, cnt, Wt_h, Wt_jk, bnsc, bnsh);
    k_deg<<<(E + 255) / 256, 256, 0, stream>>>(dst, cnt, E);
    k_scan_part<<<NB, 256, 0, stream>>>(cnt, bsum, dis, N);
    k_scan_add<<<NB, 256, 0, stream>>>(cnt, bsum, rowptr, N);
    k_scatter<<<(E + 255) / 256, 256, 0, stream>>>(src, dst, dis, rowptr, csr, E);

    // layer 0: aggregate in 9-ch space, then GEMM(K=9) + BN + ReLU
    k_aggr0<<<(N * 16 + 255) / 256, 256, 0, stream>>>(x, dis, rowptr, csr, xa, N);
    k_gemm0<<<(N + 7) / 8, 192, 0, stream>>>(xa, W0, bnsc, bnsh, xcat, N);

    // layers 1..3: GEMM -> tmp16, then fused aggregate + BN + ReLU -> xcat
    const int MB = (N + 63) / 64;   // 391
    for (int l = 1; l < 4; ++l) {
        k_mgemm<6><<<MB, 256, 0, stream>>>(xcat + (l - 1) * 192,
                                           Wt_h + (l - 1) * 192 * 192, tmp16, N);
        k_aggr_bn<<<(N + 3) / 4, 256, 0, stream>>>(tmp16, dis, rowptr, csr,
                                                   bnsc + l * 192, bnsh + l * 192,
                                                   xcat + l * 192, N);
    }

    // JK: [N x 768] @ [768 x 192] -> bf16 tmp16 (bias folded into pool)
    k_mgemm<24><<<MB, 256, 0, stream>>>(xcat, Wt_jk, tmp16, N);

    // segmented max pool + bias + output dense, no atomics
    k_pool_out<<<G, 192, 0, stream>>>(tmp16, batch, b_jk, W_out, b_out, out, N);
}

// Round 12
// 296.206 us; speedup vs baseline: 1.0623x; 1.0151x over previous
//
#include <hip/hip_runtime.h>
#include <hip/hip_bf16.h>

#define N_NODES 25000
#define N_EDGES 400000
#define N_GRAPHS 1000
#define HID 185
#define EPS 1e-5f
#define XPITCH 768            // xcat row pitch (4 * 192), bf16
#define APITCH 36             // LDS row pitch in shorts (18 dwords; conflict-free quarter-wave)

typedef __attribute__((ext_vector_type(8))) short bf16x8;
typedef __attribute__((ext_vector_type(4))) float f32x4;

__device__ __forceinline__ short f2bf(float f) {
    union { float f; unsigned u; } v; v.f = f;
    unsigned r = v.u + 0x7FFFu + ((v.u >> 16) & 1u);   // RNE
    return (short)(r >> 16);
}
__device__ __forceinline__ float bfl(unsigned u) { return __uint_as_float(u << 16); }
__device__ __forceinline__ float bfh(unsigned u) { return __uint_as_float(u & 0xFFFF0000u); }
__device__ __forceinline__ unsigned pk2(float lo, float hi) {
    return (unsigned)(unsigned short)f2bf(lo) | ((unsigned)(unsigned short)f2bf(hi) << 16);
}
// packed CSR entry: high 16 = bf16 weight, low 16 = src index (N < 65536)
__device__ __forceinline__ int csr_idx(unsigned p) { return (int)(p & 0xFFFFu); }
__device__ __forceinline__ float csr_wgt(unsigned p) { return bfh(p); }

// ---- setup: zero cnt + weight transpose/pad/bf16 + BN tables (one kernel) --
#define HW (3 * 192 * 192)
#define JW (192 * 768)
#define CNTPAD 25024
__global__ void k_setup(const float* __restrict__ W_h, const float* __restrict__ W_jk,
                        const float* __restrict__ b0, const float* __restrict__ b_h,
                        const float* __restrict__ gamma, const float* __restrict__ beta,
                        const float* __restrict__ mean, const float* __restrict__ var,
                        int* __restrict__ cnt,
                        short* __restrict__ Wt_h, short* __restrict__ Wt_jk,
                        float* __restrict__ bnsc, float* __restrict__ bnsh) {
    int idx = blockIdx.x * 256 + threadIdx.x;
    if (idx < CNTPAD) { cnt[idx] = 0; return; }
    int p = idx - CNTPAD;
    if (p < HW) {
        int l = p / (192 * 192);
        int r = p % (192 * 192);
        int n = r / 192, k = r % 192;
        float v = (n < HID && k < HID) ? W_h[(l * HID + k) * HID + n] : 0.0f;
        Wt_h[p] = f2bf(v);
    } else if (p < HW + JW) {
        int j2 = p - HW;
        int n = j2 / 768, kk = j2 % 768;
        int l = kk / 192, j = kk % 192;
        float v = (n < HID && j < HID) ? W_jk[(l * HID + j) * HID + n] : 0.0f;
        Wt_jk[j2] = f2bf(v);
    } else if (p < HW + JW + 4 * 192) {
        int li = p - HW - JW;
        int l = li / 192, c = li % 192;
        float sc = 0.0f, sh = 0.0f;
        if (c < HID) {
            float bb = (l == 0) ? b0[c] : b_h[(l - 1) * HID + c];
            sc = rsqrtf(var[l * HID + c] + EPS) * gamma[l * HID + c];
            sh = (bb - mean[l * HID + c]) * sc + beta[l * HID + c];
        }
        bnsc[li] = sc;
        bnsh[li] = sh;
    }
}

__global__ void k_deg(const int* __restrict__ dst, int* cnt, int E) {
    int i = blockIdx.x * blockDim.x + threadIdx.x;
    if (i < E) atomicAdd(&cnt[dst[i]], 1);
}

// ---- scan phase 1: per-block sums (+ dis) ----------------------------------
__global__ __launch_bounds__(256) void k_scan_part(const int* __restrict__ cnt,
                                                   int* __restrict__ bsum,
                                                   float* __restrict__ dis, int N) {
    int i = blockIdx.x * 256 + threadIdx.x;
    int v = (i < N) ? cnt[i] : 0;
    if (i < N) dis[i] = rsqrtf((float)(v + 1));
    #pragma unroll
    for (int off = 32; off; off >>= 1) v += __shfl_down(v, off);
    __shared__ int s[4];
    if ((threadIdx.x & 63) == 0) s[threadIdx.x >> 6] = v;
    __syncthreads();
    if (threadIdx.x == 0) bsum[blockIdx.x] = s[0] + s[1] + s[2] + s[3];
}

// ---- scan phase 2: exclusive prefix -> rowptr[i] (block base from bsum) ----
__global__ __launch_bounds__(256) void k_scan_add(const int* __restrict__ cnt,
                                                  const int* __restrict__ bsum,
                                                  int* __restrict__ rowptr, int N) {
    __shared__ int s[256];
    const int t = threadIdx.x;
    const int b = blockIdx.x;
    int partial = 0;
    for (int i = t; i < b; i += 256) partial += bsum[i];
    s[t] = partial; __syncthreads();
    for (int off = 128; off; off >>= 1) {
        if (t < off) s[t] += s[t + off];
        __syncthreads();
    }
    const int base = s[0];
    __syncthreads();
    int i = b * 256 + t;
    int v = (i < N) ? cnt[i] : 0;
    s[t] = v; __syncthreads();
    for (int off = 1; off < 256; off <<= 1) {
        int x2 = (t >= off) ? s[t - off] : 0;
        __syncthreads();
        s[t] += x2;
        __syncthreads();
    }
    if (i < N) rowptr[i] = base + s[t] - v;   // exclusive
}

// ---- scatter: bump rowptr (post: rowptr[n]=end; begin = n?rowptr[n-1]:0) ---
// 4B packed entry: (bf16(dis[src]) << 16) | src
__global__ void k_scatter(const int* __restrict__ src, const int* __restrict__ dst,
                          const float* __restrict__ dis,
                          int* rowptr, unsigned* __restrict__ csr, int E) {
    int e = blockIdx.x * blockDim.x + threadIdx.x;
    if (e < E) {
        int d = dst[e];
        int s = src[e];
        int o = atomicAdd(&rowptr[d], 1);
        csr[o] = ((unsigned)(unsigned short)f2bf(dis[s]) << 16) | (unsigned)s;
    }
}

// ---- layer-0 aggregation in 9-ch input space (unroll-8 MLP) ----------------
__global__ void k_aggr0(const float* __restrict__ x, const float* __restrict__ dis,
                        const int* __restrict__ rowptr, const unsigned* __restrict__ csr,
                        float* __restrict__ xa, int N) {
    int idx = blockIdx.x * blockDim.x + threadIdx.x;
    int n = idx >> 4;
    int c = idx & 15;
    if (n >= N || c >= 9) return;
    float dn = dis[n];
    float acc = x[n * 9 + c] * dn;
    int end = rowptr[n];
    int e = n ? rowptr[n - 1] : 0;
    for (; e + 8 <= end; e += 8) {
        unsigned p0 = csr[e],     p1 = csr[e + 1], p2 = csr[e + 2], p3 = csr[e + 3];
        unsigned p4 = csr[e + 4], p5 = csr[e + 5], p6 = csr[e + 6], p7 = csr[e + 7];
        float v0 = x[csr_idx(p0) * 9 + c], v1 = x[csr_idx(p1) * 9 + c];
        float v2 = x[csr_idx(p2) * 9 + c], v3 = x[csr_idx(p3) * 9 + c];
        float v4 = x[csr_idx(p4) * 9 + c], v5 = x[csr_idx(p5) * 9 + c];
        float v6 = x[csr_idx(p6) * 9 + c], v7 = x[csr_idx(p7) * 9 + c];
        acc += v0 * csr_wgt(p0) + v1 * csr_wgt(p1) + v2 * csr_wgt(p2) + v3 * csr_wgt(p3)
             + v4 * csr_wgt(p4) + v5 * csr_wgt(p5) + v6 * csr_wgt(p6) + v7 * csr_wgt(p7);
    }
    for (; e + 4 <= end; e += 4) {
        unsigned p0 = csr[e], p1 = csr[e + 1], p2 = csr[e + 2], p3 = csr[e + 3];
        acc += x[csr_idx(p0) * 9 + c] * csr_wgt(p0)
             + x[csr_idx(p1) * 9 + c] * csr_wgt(p1)
             + x[csr_idx(p2) * 9 + c] * csr_wgt(p2)
             + x[csr_idx(p3) * 9 + c] * csr_wgt(p3);
    }
    for (; e < end; ++e) {
        unsigned p = csr[e];
        acc += x[csr_idx(p) * 9 + c] * csr_wgt(p);
    }
    xa[n * 9 + c] = acc * dn;
}

// ---- layer-0 GEMM (fp32 vector, K=9) + BN + ReLU -> bf16 xcat slice 0 ------
__global__ __launch_bounds__(192) void k_gemm0(const float* __restrict__ A,
                                               const float* __restrict__ W,
                                               const float* __restrict__ bnsc,
                                               const float* __restrict__ bnsh,
                                               short* __restrict__ xcat, int N) {
    __shared__ float As[8 * 9];
    const int tid = threadIdx.x;
    const int r0 = blockIdx.x * 8;
    for (int idx = tid; idx < 72; idx += 192) {
        int r = idx & 7, k = idx >> 3;
        int row = r0 + r;
        As[idx] = (row < N) ? A[row * 9 + k] : 0.0f;
    }
    __syncthreads();
    const int c = tid;   // 0..191
    float res[8];
    #pragma unroll
    for (int r = 0; r < 8; ++r) res[r] = 0.0f;
    if (c < HID) {
        float acc[8] = {0,0,0,0,0,0,0,0};
        for (int k = 0; k < 9; ++k) {
            float w = W[k * HID + c];
            #pragma unroll
            for (int r = 0; r < 8; ++r) acc[r] += As[k * 8 + r] * w;
        }
        float sc = bnsc[c], sh = bnsh[c];
        #pragma unroll
        for (int r = 0; r < 8; ++r)
            res[r] = fmaxf(acc[r] * sc + sh, 0.0f);
    }
    #pragma unroll
    for (int r = 0; r < 8; ++r) {
        int row = r0 + r;
        if (row < N) xcat[row * XPITCH + c] = (c < HID) ? f2bf(res[r]) : (short)0;
    }
}

// ---- bf16 MFMA GEMM (R8 structure, best measured) --------------------------
// C[N x 192] = A[N x KCH*32] @ Bt^T, bf16 out at pitch 192; A pitch XPITCH.
template<int KCH>
__global__ __launch_bounds__(256) void k_mgemm(const short* __restrict__ A,
                                               const short* __restrict__ Bt,
                                               short* __restrict__ Cout, int N) {
    __shared__ short As[64 * APITCH];
    __shared__ short Bs[192 * APITCH];
    const int tid = threadIdx.x;
    const int wave = tid >> 6;
    const int lane = tid & 63;
    const int quad = lane >> 4;
    const int lm = lane & 15;
    const int r0 = blockIdx.x * 64;
    const int KTOT = KCH * 32;
    const int arow = tid >> 2, aseg = tid & 3;

    f32x4 acc[4][3];
    #pragma unroll
    for (int i = 0; i < 4; ++i)
        #pragma unroll
        for (int j = 0; j < 3; ++j) acc[i][j] = (f32x4){0.f, 0.f, 0.f, 0.f};

    for (int kc = 0; kc < KCH; ++kc) {
        const int k0 = kc * 32;
        {   // stage A: 64 rows x 32 k (16B per thread)
            int grow = r0 + arow;
            bf16x8 v = (bf16x8){0,0,0,0,0,0,0,0};
            if (grow < N) v = *(const bf16x8*)(A + (size_t)grow * XPITCH + k0 + aseg * 8);
            *(bf16x8*)(As + arow * APITCH + aseg * 8) = v;
        }
        #pragma unroll
        for (int i = 0; i < 3; ++i) {   // stage B: 192 rows x 32 k
            int u = tid + i * 256;
            int n = u >> 2, seg = u & 3;
            bf16x8 v = *(const bf16x8*)(Bt + n * KTOT + k0 + seg * 8);
            *(bf16x8*)(Bs + n * APITCH + seg * 8) = v;
        }
        __syncthreads();
        bf16x8 a[4], b[3];
        #pragma unroll
        for (int mt = 0; mt < 4; ++mt)
            a[mt] = *(const bf16x8*)(As + (mt * 16 + lm) * APITCH + quad * 8);
        #pragma unroll
        for (int nt = 0; nt < 3; ++nt)
            b[nt] = *(const bf16x8*)(Bs + (wave * 48 + nt * 16 + lm) * APITCH + quad * 8);
        #pragma unroll
        for (int mt = 0; mt < 4; ++mt)
            #pragma unroll
            for (int nt = 0; nt < 3; ++nt)
                acc[mt][nt] = __builtin_amdgcn_mfma_f32_16x16x32_bf16(a[mt], b[nt], acc[mt][nt], 0, 0, 0);
        __syncthreads();
    }
    // epilogue: D[row][col], col = wave*48+nt*16+lm, row = r0+mt*16+quad*4+r
    #pragma unroll
    for (int mt = 0; mt < 4; ++mt) {
        #pragma unroll
        for (int nt = 0; nt < 3; ++nt) {
            int col = wave * 48 + nt * 16 + lm;
            #pragma unroll
            for (int r = 0; r < 4; ++r) {
                int row = r0 + mt * 16 + quad * 4 + r;
                if (row < N) Cout[row * 192 + col] = f2bf(acc[mt][nt][r]);
            }
        }
    }
}

// ---- fused aggregation + BN + ReLU (layers 1..3), unroll-8 MLP -------------
// one node per wave; lane covers 4 channels (uint2 = 4 bf16), 48 active lanes
__global__ __launch_bounds__(256) void k_aggr_bn(const short* __restrict__ tmp16,
                                                 const float* __restrict__ dis,
                                                 const int* __restrict__ rowptr,
                                                 const unsigned* __restrict__ csr,
                                                 const float* __restrict__ bnsc,
                                                 const float* __restrict__ bnsh,
                                                 short* __restrict__ outp, int N) {
    int n = (blockIdx.x << 2) + (threadIdx.x >> 6);
    if (n >= N) return;
    int lane = threadIdx.x & 63;
    int c0 = (lane < 48) ? (lane << 2) : 0;
    float dn = dis[n];
    float a0, a1, a2, a3;
    {
        uint2 v = *(const uint2*)(tmp16 + (size_t)n * 192 + c0);
        a0 = bfl(v.x) * dn; a1 = bfh(v.x) * dn; a2 = bfl(v.y) * dn; a3 = bfh(v.y) * dn;
    }
    int end = rowptr[n];
    int e = n ? rowptr[n - 1] : 0;
    for (; e + 8 <= end; e += 8) {
        unsigned p0 = csr[e],     p1 = csr[e + 1], p2 = csr[e + 2], p3 = csr[e + 3];
        unsigned p4 = csr[e + 4], p5 = csr[e + 5], p6 = csr[e + 6], p7 = csr[e + 7];
        uint2 v0 = *(const uint2*)(tmp16 + (size_t)csr_idx(p0) * 192 + c0);
        uint2 v1 = *(const uint2*)(tmp16 + (size_t)csr_idx(p1) * 192 + c0);
        uint2 v2 = *(const uint2*)(tmp16 + (size_t)csr_idx(p2) * 192 + c0);
        uint2 v3 = *(const uint2*)(tmp16 + (size_t)csr_idx(p3) * 192 + c0);
        uint2 v4 = *(const uint2*)(tmp16 + (size_t)csr_idx(p4) * 192 + c0);
        uint2 v5 = *(const uint2*)(tmp16 + (size_t)csr_idx(p5) * 192 + c0);
        uint2 v6 = *(const uint2*)(tmp16 + (size_t)csr_idx(p6) * 192 + c0);
        uint2 v7 = *(const uint2*)(tmp16 + (size_t)csr_idx(p7) * 192 + c0);
        float w0 = csr_wgt(p0), w1 = csr_wgt(p1), w2 = csr_wgt(p2), w3 = csr_wgt(p3);
        float w4 = csr_wgt(p4), w5 = csr_wgt(p5), w6 = csr_wgt(p6), w7 = csr_wgt(p7);
        a0 += bfl(v0.x) * w0; a1 += bfh(v0.x) * w0; a2 += bfl(v0.y) * w0; a3 += bfh(v0.y) * w0;
        a0 += bfl(v1.x) * w1; a1 += bfh(v1.x) * w1; a2 += bfl(v1.y) * w1; a3 += bfh(v1.y) * w1;
        a0 += bfl(v2.x) * w2; a1 += bfh(v2.x) * w2; a2 += bfl(v2.y) * w2; a3 += bfh(v2.y) * w2;
        a0 += bfl(v3.x) * w3; a1 += bfh(v3.x) * w3; a2 += bfl(v3.y) * w3; a3 += bfh(v3.y) * w3;
        a0 += bfl(v4.x) * w4; a1 += bfh(v4.x) * w4; a2 += bfl(v4.y) * w4; a3 += bfh(v4.y) * w4;
        a0 += bfl(v5.x) * w5; a1 += bfh(v5.x) * w5; a2 += bfl(v5.y) * w5; a3 += bfh(v5.y) * w5;
        a0 += bfl(v6.x) * w6; a1 += bfh(v6.x) * w6; a2 += bfl(v6.y) * w6; a3 += bfh(v6.y) * w6;
        a0 += bfl(v7.x) * w7; a1 += bfh(v7.x) * w7; a2 += bfl(v7.y) * w7; a3 += bfh(v7.y) * w7;
    }
    for (; e + 4 <= end; e += 4) {
        unsigned p0 = csr[e], p1 = csr[e + 1], p2 = csr[e + 2], p3 = csr[e + 3];
        float w0 = csr_wgt(p0), w1 = csr_wgt(p1), w2 = csr_wgt(p2), w3 = csr_wgt(p3);
        uint2 v0 = *(const uint2*)(tmp16 + (size_t)csr_idx(p0) * 192 + c0);
        uint2 v1 = *(const uint2*)(tmp16 + (size_t)csr_idx(p1) * 192 + c0);
        uint2 v2 = *(const uint2*)(tmp16 + (size_t)csr_idx(p2) * 192 + c0);
        uint2 v3 = *(const uint2*)(tmp16 + (size_t)csr_idx(p3) * 192 + c0);
        a0 += bfl(v0.x) * w0; a1 += bfh(v0.x) * w0; a2 += bfl(v0.y) * w0; a3 += bfh(v0.y) * w0;
        a0 += bfl(v1.x) * w1; a1 += bfh(v1.x) * w1; a2 += bfl(v1.y) * w1; a3 += bfh(v1.y) * w1;
        a0 += bfl(v2.x) * w2; a1 += bfh(v2.x) * w2; a2 += bfl(v2.y) * w2; a3 += bfh(v2.y) * w2;
        a0 += bfl(v3.x) * w3; a1 += bfh(v3.x) * w3; a2 += bfl(v3.y) * w3; a3 += bfh(v3.y) * w3;
    }
    for (; e < end; ++e) {
        unsigned p = csr[e];
        float w = csr_wgt(p);
        uint2 v = *(const uint2*)(tmp16 + (size_t)csr_idx(p) * 192 + c0);
        a0 += bfl(v.x) * w; a1 += bfh(v.x) * w; a2 += bfl(v.y) * w; a3 += bfh(v.y) * w;
    }
    float4 sc = *(const float4*)(bnsc + c0);
    float4 sh = *(const float4*)(bnsh + c0);
    float o0 = fmaxf(a0 * dn * sc.x + sh.x, 0.0f);
    float o1 = fmaxf(a1 * dn * sc.y + sh.y, 0.0f);
    float o2 = fmaxf(a2 * dn * sc.z + sh.z, 0.0f);
    float o3 = fmaxf(a3 * dn * sc.w + sh.w, 0.0f);
    if (lane < 48) {
        uint2 p;
        p.x = pk2(o0, o1);
        p.y = pk2(o2, o3);
        *(uint2*)(outp + (size_t)n * XPITCH + c0) = p;
    }
}

// ---- segmented global-max-pool + bias + final dense, one block per graph ---
__global__ __launch_bounds__(192) void k_pool_out(const short* __restrict__ jk,
                                                  const int* __restrict__ batch,
                                                  const float* __restrict__ b_jk,
                                                  const float* __restrict__ W_out,
                                                  const float* __restrict__ b_out,
                                                  float* __restrict__ out, int N) {
    __shared__ int bounds[2];
    __shared__ float partial[3];
    const int g = blockIdx.x;
    const int tid = threadIdx.x;
    if (tid < 2) {
        int key = g + tid;              // lower_bound(batch, key)
        int lo = 0, hi = N;
        while (lo < hi) {
            int mid = (lo + hi) >> 1;
            if (batch[mid] < key) lo = mid + 1; else hi = mid;
        }
        bounds[tid] = lo;
    }
    __syncthreads();
    const int beg = bounds[0], end = bounds[1];
    float mx = -3.4e38f;
    for (int n = beg; n < end; ++n)
        mx = fmaxf(mx, bfl((unsigned)(unsigned short)jk[(size_t)n * 192 + tid]));
    float p = (tid < HID) ? (mx + b_jk[tid]) * W_out[tid] : 0.0f;
    #pragma unroll
    for (int off = 32; off; off >>= 1) p += __shfl_down(p, off);
    if ((tid & 63) == 0) partial[tid >> 6] = p;
    __syncthreads();
    if (tid == 0) out[g] = partial[0] + partial[1] + partial[2] + b_out[0];
}

extern "C" void kernel_launch(void* const* d_in, const int* in_sizes, int n_in,
                              void* d_out, int out_size, void* d_ws, size_t ws_size,
                              hipStream_t stream) {
    const float* x      = (const float*)d_in[0];
    const int*   ei     = (const int*)  d_in[1];
    const int*   batch  = (const int*)  d_in[2];
    const float* W0     = (const float*)d_in[3];
    const float* b0     = (const float*)d_in[4];
    const float* W_h    = (const float*)d_in[5];
    const float* b_h    = (const float*)d_in[6];
    const float* gamma  = (const float*)d_in[7];
    const float* beta   = (const float*)d_in[8];
    const float* mean   = (const float*)d_in[9];
    const float* var    = (const float*)d_in[10];
    const float* W_jk   = (const float*)d_in[11];
    const float* b_jk   = (const float*)d_in[12];
    const float* W_out  = (const float*)d_in[13];
    const float* b_out  = (const float*)d_in[14];
    float* out = (float*)d_out;

    const int N = N_NODES, E = N_EDGES, G = N_GRAPHS;
    const int NB = (N + 255) / 256;   // 98

    // workspace layout (8B-aligned chunks)
    float* dis   = (float*)d_ws;                    // 25,024
    float* xa    = dis + 25024;                     // 225,024
    float* bnsc  = xa + 225024;                     // 768
    float* bnsh  = bnsc + 768;                      // 768
    unsigned* csr = (unsigned*)(bnsh + 768);        // 400,000 packed entries
    short* xcat  = (short*)(csr + 400000);          // 19,200,000 shorts
    short* tmp16 = xcat + 19200000;                 // 4,800,000 shorts (aggr in / JK out)
    short* Wt_h  = tmp16 + 4800000;                 // 110,592 shorts
    short* Wt_jk = Wt_h + 110592;                   // 147,456 shorts
    int* rowptr  = (int*)(Wt_jk + 147456);          // 25,024
    int* cnt     = rowptr + 25024;                  // 25,024
    int* bsum    = cnt + 25024;                     // 128

    const int* src = ei;
    const int* dst = ei + E;

    k_setup<<<(CNTPAD + HW + JW + 4 * 192 + 255) / 256, 256, 0, stream>>>(
        W_h, W_jk, b0, b_h, gamma, beta, mean, var, cnt, Wt_h, Wt_jk, bnsc, bnsh);
    k_deg<<<(E + 255) / 256, 256, 0, stream>>>(dst, cnt, E);
    k_scan_part<<<NB, 256, 0, stream>>>(cnt, bsum, dis, N);
    k_scan_add<<<NB, 256, 0, stream>>>(cnt, bsum, rowptr, N);
    k_scatter<<<(E + 255) / 256, 256, 0, stream>>>(src, dst, dis, rowptr, csr, E);

    // layer 0: aggregate in 9-ch space, then GEMM(K=9) + BN + ReLU
    k_aggr0<<<(N * 16 + 255) / 256, 256, 0, stream>>>(x, dis, rowptr, csr, xa, N);
    k_gemm0<<<(N + 7) / 8, 192, 0, stream>>>(xa, W0, bnsc, bnsh, xcat, N);

    // layers 1..3: GEMM -> tmp16, then fused aggregate + BN + ReLU -> xcat
    const int MB = (N + 63) / 64;   // 391
    for (int l = 1; l < 4; ++l) {
        k_mgemm<6><<<MB, 256, 0, stream>>>(xcat + (l - 1) * 192,
                                           Wt_h + (l - 1) * 192 * 192, tmp16, N);
        k_aggr_bn<<<(N + 3) / 4, 256, 0, stream>>>(tmp16, dis, rowptr, csr,
                                                   bnsc + l * 192, bnsh + l * 192,
                                                   xcat + l * 192, N);
    }

    // JK: [N x 768] @ [768 x 192] -> bf16 tmp16 (bias folded into pool)
    k_mgemm<24><<<MB, 256, 0, stream>>>(xcat, Wt_jk, tmp16, N);

    // segmented max pool + bias + output dense, no atomics
    k_pool_out<<<G, 192, 0, stream>>>(tmp16, batch, b_jk, W_out, b_out, out, N);
}